// Round 1
// baseline (150.239 us; speedup 1.0000x reference)
//
#include <hip/hip_runtime.h>
#include <hip/hip_bf16.h>

#define DDIM 448
#define NSTEP 14            // 448 / 32

typedef __hip_bfloat16 bf16;
typedef __attribute__((ext_vector_type(8))) short short8;   // 8 bf16 = 16B (MFMA A/B frag)
typedef __attribute__((ext_vector_type(4))) float f32x4;    // MFMA C/D frag / float4

__device__ __forceinline__ short bf_bits(float f) {
    bf16 h = __float2bfloat16(f);
    return *reinterpret_cast<short*>(&h);
}

// async global->LDS DMA: per-lane 16B; LDS dst = wave-uniform base + lane*16
__device__ __forceinline__ void async16(const bf16* g, bf16* l) {
    __builtin_amdgcn_global_load_lds(
        (const __attribute__((address_space(1))) void*)g,
        (__attribute__((address_space(3))) void*)l, 16, 0, 0);
}

// ---------------------------------------------------------------------------
// Kernel 1: WcT[o][i] = sum_d Wo[d][o] * E[i][d],
//           E[i][d] = Wq[i][d]*diagA[d] + Wk[i][d]*diagB[d] + Wv[i][d]*diagC[d]
// (unchanged — passed, ~5 µs)
// ---------------------------------------------------------------------------
__global__ __launch_bounds__(256) void prep_wc(
    const float* __restrict__ Wq, const float* __restrict__ Wk,
    const float* __restrict__ Wv, const float* __restrict__ Wo,
    const float* __restrict__ Ad, const float* __restrict__ Bd,
    const float* __restrict__ Cd, bf16* __restrict__ WcT)
{
    __shared__ __align__(16) bf16 As[64 * 32];
    __shared__ __align__(16) bf16 Bs[64 * 32];
    __shared__ float da[DDIM], db[DDIM], dc[DDIM];

    const int tid  = threadIdx.x;
    const int i0   = blockIdx.x * 64;
    const int o0   = blockIdx.y * 64;
    const int lane = tid & 63;
    const int wid  = tid >> 6;
    const int wm   = wid >> 1, wn = wid & 1;
    const int m_   = lane & 15, kq = lane >> 4;

    for (int d = tid; d < DDIM; d += 256) {
        da[d] = Ad[d * DDIM + d];
        db[d] = Bd[d * DDIM + d];
        dc[d] = Cd[d * DDIM + d];
    }

    const int dr  = tid >> 3;
    const int oc8 = (tid & 7) * 8;
    const int ir  = tid >> 2;
    const int dc8 = (tid & 3) * 8;

    f32x4 acc[2][2] = {};

    f32x4 w0 = *(const f32x4*)(Wo + dr * DDIM + o0 + oc8);
    f32x4 w1 = *(const f32x4*)(Wo + dr * DDIM + o0 + oc8 + 4);
    f32x4 q0 = *(const f32x4*)(Wq + (i0 + ir) * DDIM + dc8);
    f32x4 q1 = *(const f32x4*)(Wq + (i0 + ir) * DDIM + dc8 + 4);
    f32x4 t0 = *(const f32x4*)(Wk + (i0 + ir) * DDIM + dc8);
    f32x4 t1 = *(const f32x4*)(Wk + (i0 + ir) * DDIM + dc8 + 4);
    f32x4 v0 = *(const f32x4*)(Wv + (i0 + ir) * DDIM + dc8);
    f32x4 v1 = *(const f32x4*)(Wv + (i0 + ir) * DDIM + dc8 + 4);

    for (int k0 = 0; k0 < DDIM; k0 += 32) {
        __syncthreads();
        #pragma unroll
        for (int j = 0; j < 4; ++j) {
            As[(oc8 + j) * 32 + dr]     = __float2bfloat16(w0[j]);
            As[(oc8 + 4 + j) * 32 + dr] = __float2bfloat16(w1[j]);
        }
        short8 e;
        #pragma unroll
        for (int j = 0; j < 4; ++j) {
            e[j]     = bf_bits(q0[j] * da[k0 + dc8 + j]
                             + t0[j] * db[k0 + dc8 + j]
                             + v0[j] * dc[k0 + dc8 + j]);
            e[j + 4] = bf_bits(q1[j] * da[k0 + dc8 + 4 + j]
                             + t1[j] * db[k0 + dc8 + 4 + j]
                             + v1[j] * dc[k0 + dc8 + 4 + j]);
        }
        *(short8*)&Bs[ir * 32 + dc8] = e;
        __syncthreads();

        const int kn = (k0 + 32 < DDIM) ? k0 + 32 : 0;
        w0 = *(const f32x4*)(Wo + (kn + dr) * DDIM + o0 + oc8);
        w1 = *(const f32x4*)(Wo + (kn + dr) * DDIM + o0 + oc8 + 4);
        q0 = *(const f32x4*)(Wq + (i0 + ir) * DDIM + kn + dc8);
        q1 = *(const f32x4*)(Wq + (i0 + ir) * DDIM + kn + dc8 + 4);
        t0 = *(const f32x4*)(Wk + (i0 + ir) * DDIM + kn + dc8);
        t1 = *(const f32x4*)(Wk + (i0 + ir) * DDIM + kn + dc8 + 4);
        v0 = *(const f32x4*)(Wv + (i0 + ir) * DDIM + kn + dc8);
        v1 = *(const f32x4*)(Wv + (i0 + ir) * DDIM + kn + dc8 + 4);

        short8 af[2], bfr[2];
        #pragma unroll
        for (int mi = 0; mi < 2; ++mi)
            af[mi] = *(const short8*)&As[(wm * 32 + mi * 16 + m_) * 32 + kq * 8];
        #pragma unroll
        for (int ni = 0; ni < 2; ++ni)
            bfr[ni] = *(const short8*)&Bs[(wn * 32 + ni * 16 + m_) * 32 + kq * 8];
        #pragma unroll
        for (int mi = 0; mi < 2; ++mi)
            #pragma unroll
            for (int ni = 0; ni < 2; ++ni)
                acc[mi][ni] = __builtin_amdgcn_mfma_f32_16x16x32_bf16(
                    af[mi], bfr[ni], acc[mi][ni], 0, 0, 0);
    }

    #pragma unroll
    for (int mi = 0; mi < 2; ++mi)
        #pragma unroll
        for (int ni = 0; ni < 2; ++ni) {
            const int o = o0 + wm * 32 + mi * 16 + kq * 4;
            const int i = i0 + wn * 32 + ni * 16 + m_;
            #pragma unroll
            for (int r = 0; r < 4; ++r)
                WcT[(o + r) * DDIM + i] = __float2bfloat16(acc[mi][ni][r]);
        }
}

// ---------------------------------------------------------------------------
// Kernel 2: out[M x 448](fp32) = X(fp32) @ Wc    (WcT bf16, o-major, i contig)
// v2: BM=64 (was 128) -> acc[4][7], LDS 64 KB/block, ~190 VGPR ->
// 2 blocks/CU (__launch_bounds__(256,2), grid 512). When one block stalls
// on its per-K-step barrier drain (vmcnt(0) for the B DMA) or runs its
// LDS-bounce epilogue, the co-resident block keeps MFMA + the X read
// stream busy. Same fragment layouts / index algebra as the verified v1.
// smem: A0 @0 (4K), A1 @4K (4K), B0 @8K (28K), B1 @36K (28K) = 64 KB;
// epilogue bounce Cb aliases @8K (32x448 fp32 = 56 KB).
// ---------------------------------------------------------------------------
__global__ __launch_bounds__(256, 2) void gemm_xwc(
    const float* __restrict__ X, const bf16* __restrict__ WcT,
    float* __restrict__ out)
{
    __shared__ __align__(16) char smem[65536];          // 64 KB

    const int tid  = threadIdx.x;
    const int lane = tid & 63;
    const int wid  = tid >> 6;               // col quarter: 112 cols
    const int m_   = lane & 15;
    const int kq   = lane >> 4;
    const int row0 = blockIdx.x * 64;

    // A staging: 64x32 fp32 -> 8 elem/thread
    const int ar = tid >> 2;                 // 0..63
    const int ac = (tid & 3) * 8;            // 0,8,16,24
    const float* agp = X + (row0 + ar) * DDIM + ac;

    // B DMA lane map: instr j covers rows (wid*7+j)*16 + lrow, 64B per row
    const int lrow = lane >> 2;
    const int lcol = (lane & 3) * 8;
    const bf16* bgp = WcT + (wid * 112 + lrow) * DDIM + lcol;

    f32x4 acc[4][7] = {};

    // ---- prologue: DMA B(0); load+stage A(0); prefetch a-regs for k=32
    {
        bf16* B0 = (bf16*)(smem + 8192);
        #pragma unroll
        for (int j = 0; j < 7; ++j)
            async16(bgp + j * 16 * DDIM, B0 + (wid * 7 + j) * 16 * 32);
    }

    f32x4 a0 = *(const f32x4*)(agp);
    f32x4 a1 = *(const f32x4*)(agp + 4);
    {
        bf16* A0 = (bf16*)smem;
        short8 w;
        #pragma unroll
        for (int j = 0; j < 4; ++j) {
            w[j] = bf_bits(a0[j]); w[j + 4] = bf_bits(a1[j]);
        }
        *(short8*)&A0[ar * 32 + ac] = w;     // byte addr = tid*16: conflict-free
    }
    a0 = *(const f32x4*)(agp + 32);
    a1 = *(const f32x4*)(agp + 36);
    __syncthreads();                          // drains DMA(0), A(0) writes

    for (int s = 0; s < NSTEP; ++s) {
        const int cur = s & 1, nxt = cur ^ 1;
        const bf16* Ac = (const bf16*)(smem + (cur << 12));          // 0 / 4K
        const bf16* Bc = (const bf16*)(smem + 8192 + cur * 28672);   // 8K / 36K

        if (s + 1 < NSTEP) {                  // uniform
            bf16* An = (bf16*)(smem + (nxt << 12));
            bf16* Bn = (bf16*)(smem + 8192 + nxt * 28672);
            // stage A(next) from regs (hold k=(s+1)*32)
            short8 w;
            #pragma unroll
            for (int j = 0; j < 4; ++j) {
                w[j] = bf_bits(a0[j]); w[j + 4] = bf_bits(a1[j]);
            }
            *(short8*)&An[ar * 32 + ac] = w;
            // DMA B(next)
            const int kn = (s + 1) * 32;
            #pragma unroll
            for (int j = 0; j < 7; ++j)
                async16(bgp + j * 16 * DDIM + kn, Bn + (wid * 7 + j) * 16 * 32);
            // prefetch a-regs for k=(s+2)*32
            if (s + 2 < NSTEP) {              // uniform
                const int k2 = (s + 2) * 32;
                a0 = *(const f32x4*)(agp + k2);
                a1 = *(const f32x4*)(agp + k2 + 4);
            }
        }

        short8 af[4], bfr[7];
        #pragma unroll
        for (int mi = 0; mi < 4; ++mi)
            af[mi] = *(const short8*)&Ac[(mi * 16 + m_) * 32 + kq * 8];
        #pragma unroll
        for (int ni = 0; ni < 7; ++ni)
            bfr[ni] = *(const short8*)&Bc[(wid * 112 + ni * 16 + m_) * 32 + kq * 8];

        #pragma unroll
        for (int mi = 0; mi < 4; ++mi)
            #pragma unroll
            for (int ni = 0; ni < 7; ++ni)
                acc[mi][ni] = __builtin_amdgcn_mfma_f32_16x16x32_bf16(
                    af[mi], bfr[ni], acc[mi][ni], 0, 0, 0);

        __syncthreads();   // cur fully read; next buffers + vmem drained
    }

    // ---- epilogue: 2 stages of 32 rows; LDS bounce -> coalesced f32x4 stores
    float* Cb = (float*)(smem + 8192);        // 32x448 fp32 (aliases B buffers)
    #pragma unroll
    for (int t = 0; t < 2; ++t) {
        #pragma unroll
        for (int mi2 = 0; mi2 < 2; ++mi2) {
            const int mi = t * 2 + mi2;
            #pragma unroll
            for (int ni = 0; ni < 7; ++ni) {
                const int col = wid * 112 + ni * 16 + m_;
                #pragma unroll
                for (int r = 0; r < 4; ++r)
                    Cb[(mi2 * 16 + kq * 4 + r) * DDIM + col] = acc[mi][ni][r];
            }
        }
        __syncthreads();
        float* dst = out + (row0 + t * 32) * DDIM;    // 32x448 contiguous
        #pragma unroll
        for (int j = 0; j < 14; ++j)
            ((f32x4*)dst)[j * 256 + tid] = ((const f32x4*)Cb)[j * 256 + tid];
        __syncthreads();   // before next stage overwrites Cb
    }
}

// ---------------------------------------------------------------------------
extern "C" void kernel_launch(void* const* d_in, const int* in_sizes, int n_in,
                              void* d_out, int out_size, void* d_ws, size_t ws_size,
                              hipStream_t stream) {
    const float* x  = (const float*)d_in[0];
    const float* Wq = (const float*)d_in[1];
    const float* Wk = (const float*)d_in[2];
    const float* Wv = (const float*)d_in[3];
    const float* Wo = (const float*)d_in[4];
    const float* Ad = (const float*)d_in[5];
    const float* Bd = (const float*)d_in[6];
    const float* Cd = (const float*)d_in[7];

    bf16*  WcT = (bf16*)d_ws;                      // 448*448*2 = 392 KiB scratch
    float* out = (float*)d_out;

    const int M = in_sizes[0] / DDIM;              // 32768

    prep_wc<<<dim3(7, 7), 256, 0, stream>>>(Wq, Wk, Wv, Wo, Ad, Bd, Cd, WcT);
    gemm_xwc<<<M / 64, 256, 0, stream>>>(x, WcT, out);
}